// Round 3
// baseline (319.269 us; speedup 1.0000x reference)
//
#include <hip/hip_runtime.h>

// DVDNMixer: 8-fold PMF convolution (51 atoms -> 401) + C51 projection to 51 atoms.
//
// Projection is exact-integer: support=linspace(-80,80,401), delta=0.4 =>
//   out[0] = sum q[0..175]; out[j] = q[175+j] (1<=j<=49); out[50] = sum q[225..400]
//
// One wave per (b,t) task, 4 waves/block, per-wave zero-padded LDS ping-pong
// buffers. Per step each lane computes R consecutive outputs (R multiple of 4):
//   - window reads are 16B-aligned ds_read_b128 (R=4: contiguous across lanes)
//   - p[j] is wave-uniform: readfirstlane'd task index => scalar s_load => FMA
//     with SGPR operand (no v_readlane, no LDS broadcast)
//   - outputs beyond L_out compute to exact zeros (zero-padded input), so no
//     write guards; zero-invariants hold inductively.
// Step 7 keeps results in registers and feeds the projection directly.

#define N_ATOM  51
#define N_TASKS 32768            // BS*T = 128*256
#define WPB     4
#define PAD     52               // left zero pad, floats (16B multiple)
#define BUFSZ   576              // floats; max read = lane63,R=8: 504+60=564

// Computes acc[0..R) = conv outputs at positions lane*R + r of (q_in (*) p).
// bin is the buffer base; q[k] lives at bin[PAD+k]; W[x] = bin[lane*R + x];
// q[o-j] = bin[PAD + o0 + r - j] = W[PAD + r - j], indices in [2, R+51].
template<int R>
__device__ __forceinline__ void conv_body(const float* __restrict__ gp,
                                          const float* bin, float* acc, int lane) {
  constexpr int NW = (R + PAD + 3) / 4;      // float4 window reads
  const int o0 = lane * R;                   // 16B-aligned (R%4==0)
  float W[NW * 4];
  const float4* src = reinterpret_cast<const float4*>(bin + o0);
#pragma unroll
  for (int w = 0; w < NW; ++w) {
    float4 v = src[w];
    W[4 * w + 0] = v.x; W[4 * w + 1] = v.y;
    W[4 * w + 2] = v.z; W[4 * w + 3] = v.w;
  }
  float p[N_ATOM];                           // uniform addr -> s_load -> SGPRs
#pragma unroll
  for (int j = 0; j < N_ATOM; ++j) p[j] = gp[j];
#pragma unroll
  for (int r = 0; r < R; ++r) acc[r] = 0.f;
#pragma unroll
  for (int j = 0; j < N_ATOM; ++j)
#pragma unroll
    for (int r = 0; r < R; ++r)
      acc[r] = fmaf(p[j], W[PAD + r - j], acc[r]);
}

template<int R>
__device__ __forceinline__ void conv_step(const float* __restrict__ gp,
                                          const float* bin, float* bout, int lane) {
  float acc[R];
  conv_body<R>(gp, bin, acc, lane);
  float4* dst = reinterpret_cast<float4*>(bout + PAD + lane * R);  // 16B-aligned
#pragma unroll
  for (int r4 = 0; r4 < R / 4; ++r4)
    dst[r4] = make_float4(acc[4 * r4], acc[4 * r4 + 1],
                          acc[4 * r4 + 2], acc[4 * r4 + 3]);
}

__global__ __launch_bounds__(256)
void dvdn_mixer_kernel(const float* __restrict__ in, float* __restrict__ out) {
  __shared__ __align__(16) float buf[WPB][2][BUFSZ];
  const int lane = threadIdx.x & 63;
  const int wave = threadIdx.x >> 6;
  const int task = __builtin_amdgcn_readfirstlane(blockIdx.x * WPB + wave);

  const float* gp = in + (size_t)task * (8 * N_ATOM);
  float* b0 = buf[wave][0];
  float* b1 = buf[wave][1];

  // b0 <- {zeros[0,PAD), agent0[PAD,PAD+51), zeros[..,BUFSZ)} in one pass
  // (disjoint addresses: no intra-wave write-order hazard). b1 needs only its
  // left pad zeroed (every region of b1 that is ever read was written by the
  // preceding step, which writes exact zeros beyond its L_out).
  {
    float4* z0 = reinterpret_cast<float4*>(b0);
#pragma unroll
    for (int k = lane; k < BUFSZ / 4; k += 64) {
      const int f = 4 * k - PAD;             // q-index of component .x
      float4 v = make_float4(0.f, 0.f, 0.f, 0.f);
      if (f >= 0 && f + 3 < N_ATOM) {
        v.x = gp[f]; v.y = gp[f + 1]; v.z = gp[f + 2]; v.w = gp[f + 3];
      } else if (f + 3 >= 0 && f < N_ATOM) {
        if (f >= 0)         v.x = gp[f];
        if (f + 1 >= 0 && f + 1 < N_ATOM) v.y = gp[f + 1];
        if (f + 2 >= 0 && f + 2 < N_ATOM) v.z = gp[f + 2];
        if (f + 3 < N_ATOM) v.w = gp[f + 3];
      }
      z0[k] = v;
    }
    float4* z1 = reinterpret_cast<float4*>(b1);
    if (lane < PAD / 4) z1[lane] = make_float4(0.f, 0.f, 0.f, 0.f);
  }
  __syncthreads();

  // L_out: 101,151,201,251 (R=4, covers 256) ; 301,351 (R=8) ; 401 handled last
  conv_step<4>(gp + 1 * N_ATOM, b0, b1, lane); __syncthreads();
  conv_step<4>(gp + 2 * N_ATOM, b1, b0, lane); __syncthreads();
  conv_step<4>(gp + 3 * N_ATOM, b0, b1, lane); __syncthreads();
  conv_step<4>(gp + 4 * N_ATOM, b1, b0, lane); __syncthreads();
  conv_step<8>(gp + 5 * N_ATOM, b0, b1, lane); __syncthreads();
  conv_step<8>(gp + 6 * N_ATOM, b1, b0, lane); __syncthreads();

  // Step 7: keep q[8*lane .. 8*lane+8) in registers, project directly.
  float acc[8];
  conv_body<8>(gp + 7 * N_ATOM, b0, acc, lane);

  float s0 = 0.f, s1 = 0.f;
  float* o = out + (size_t)task * N_ATOM;
#pragma unroll
  for (int r = 0; r < 8; ++r) {
    const int oidx = 8 * lane + r;           // 0..511; q beyond 400 is exact 0
    if (oidx >= 176 && oidx < 225) o[oidx - 175] = acc[r];
    s0 += (oidx < 176) ? acc[r] : 0.f;
    s1 += (oidx >= 225) ? acc[r] : 0.f;
  }
#pragma unroll
  for (int d = 1; d < 64; d <<= 1) {
    s0 += __shfl_xor(s0, d, 64);
    s1 += __shfl_xor(s1, d, 64);
  }
  if (lane == 0) { o[0] = s0; o[50] = s1; }
}

extern "C" void kernel_launch(void* const* d_in, const int* in_sizes, int n_in,
                              void* d_out, int out_size, void* d_ws, size_t ws_size,
                              hipStream_t stream) {
  const float* agent_qs = (const float*)d_in[0];  // [128,256,8,51] f32
  // d_in[1] (states) is unused by the reference computation
  float* out = (float*)d_out;                     // [128,256,51] f32
  dvdn_mixer_kernel<<<N_TASKS / WPB, 256, 0, stream>>>(agent_qs, out);
}

// Round 4
// 231.779 us; speedup vs baseline: 1.3775x; 1.3775x over previous
//
#include <hip/hip_runtime.h>

// DVDNMixer: 8-fold PMF convolution (51 atoms -> 401) + C51 projection to 51.
//
// Projection is exact-integer: support=linspace(-80,80,401), delta=0.4 =>
//   out[0] = sum q[0..175]; out[j] = q[175+j] (1<=j<=49); out[50] = sum q[225..400]
//
// One wave per (b,t) task; per-wave zero-padded LDS ping-pong buffers (waves
// are fully independent: NO __syncthreads, only per-wave lgkmcnt waits).
// Per step each lane computes R consecutive outputs:
//   - window loads are VOLATILE float4 LDS reads => compiler must emit
//     ds_read_b128 and keep the window in VGPRs (R1 regression post-mortem:
//     non-volatile array was rematerialized into per-use ds_read_b32 at
//     VGPR_Count=36 with 9.7e7 bank conflicts)
//   - LDS uses a holed layout phys(L) = L + 4*(L>>3) (16B hole per 32B):
//     R=8 b128 reads hit all 8 bank-quads per 8 lanes (conflict-free; linear
//     32B stride would be 2-way), R=4 ~7/8 quads. Chunks at logical mod-8
//     in {0,4} never straddle a hole; holes are never read.
//   - p[j] is wave-uniform (readfirstlane'd task) => scalar s_load => FMA
//     with SGPR operand
//   - outputs beyond L_out compute to exact zeros (zero-padded windows), so
//     writes are unguarded; zero-invariants hold inductively.
// Step 7 keeps results in registers and feeds the projection directly.

typedef float f4 __attribute__((ext_vector_type(4)));

#define N_ATOM  51
#define N_TASKS 32768            // BS*T = 128*256
#define WPB     4
#define PAD     52               // logical left zero pad (floats)
#define LBUF    576              // logical floats per buffer

__device__ __forceinline__ constexpr int PF(int L) {   // logical->physical float idx
  return L + ((L >> 3) << 2);
}
#define PBUF 864                 // PF(576): physical floats per buffer

__device__ __forceinline__ void wait_lds() {
  asm volatile("s_waitcnt lgkmcnt(0)" ::: "memory");
}

// acc[0..R) = conv outputs at positions lane*R + r of (q_in (*) p).
// q[k] at logical bin[PAD+k]; window W[x] = logical bin[o0+x]; the FMA uses
// W[PAD + r - j], x in [2, R+52) subset of [0, 4*NW).
template<int R>
__device__ __forceinline__ void conv_body(const float* __restrict__ gp,
                                          const float* bin, float* acc, int lane) {
  constexpr int NW = (R + PAD) / 4;          // 14 (R=4) / 15 (R=8)
  const int o0 = lane * R;

  wait_lds();                                // prior step's stores -> visible

  float W[NW * 4];
#pragma unroll
  for (int m = 0; m < NW; ++m) {
    f4 v = *(const volatile f4*)(bin + PF(o0 + 4 * m));
    W[4 * m + 0] = v.x; W[4 * m + 1] = v.y;
    W[4 * m + 2] = v.z; W[4 * m + 3] = v.w;
  }
  float p[N_ATOM];                           // uniform addr -> s_load -> SGPRs
#pragma unroll
  for (int j = 0; j < N_ATOM; ++j) p[j] = gp[j];
#pragma unroll
  for (int r = 0; r < R; ++r) acc[r] = 0.f;
#pragma unroll
  for (int j = 0; j < N_ATOM; ++j)
#pragma unroll
    for (int r = 0; r < R; ++r)
      acc[r] = fmaf(p[j], W[PAD + r - j], acc[r]);
}

template<int R>
__device__ __forceinline__ void conv_step(const float* __restrict__ gp,
                                          const float* bin, float* bout, int lane) {
  float acc[R];
  conv_body<R>(gp, bin, acc, lane);
#pragma unroll
  for (int r4 = 0; r4 < R / 4; ++r4) {
    f4 v = { acc[4 * r4 + 0], acc[4 * r4 + 1], acc[4 * r4 + 2], acc[4 * r4 + 3] };
    *(volatile f4*)(bout + PF(PAD + lane * R + 4 * r4)) = v;
  }
}

__global__ __launch_bounds__(256)
void dvdn_mixer_kernel(const float* __restrict__ in, float* __restrict__ out) {
  __shared__ __align__(16) float buf[WPB][2][PBUF];
  const int lane = threadIdx.x & 63;
  const int wave = threadIdx.x >> 6;
  const int task = __builtin_amdgcn_readfirstlane(blockIdx.x * WPB + wave);

  const float* gp = in + (size_t)task * (8 * N_ATOM);
  float* b0 = buf[wave][0];
  float* b1 = buf[wave][1];

  // Init b0: all 144 logical chunks = {zeros, agent0 at [PAD,PAD+51)}.
  // Regions beyond [PAD,PAD+308) of b0 are never re-written (R=4 steps write
  // [PAD,PAD+256)), so their init zeros serve steps 5/7's wider windows.
#pragma unroll
  for (int k = lane; k < LBUF / 4; k += 64) {
    const int f = 4 * k - PAD;               // agent0 q-index of component .x
    f4 v = { 0.f, 0.f, 0.f, 0.f };
    if (f >= 0 && f + 3 < N_ATOM) {
      v.x = gp[f]; v.y = gp[f + 1]; v.z = gp[f + 2]; v.w = gp[f + 3];
    } else if (f + 3 >= 0 && f < N_ATOM) {
      if (f >= 0)                       v.x = gp[f];
      if (f + 1 >= 0 && f + 1 < N_ATOM) v.y = gp[f + 1];
      if (f + 2 >= 0 && f + 2 < N_ATOM) v.z = gp[f + 2];
      if (f + 3 < N_ATOM)               v.w = gp[f + 3];
    }
    *(volatile f4*)(b0 + PF(4 * k)) = v;
  }
  // Init b1: left pad only (everything else b1 ever serves is written by the
  // preceding step before being read: step5 (R=8) covers [PAD, PAD+512) > 564 max read).
#pragma unroll
  for (int k = lane; k < PAD / 4; k += 64) {
    f4 z = { 0.f, 0.f, 0.f, 0.f };
    *(volatile f4*)(b1 + PF(4 * k)) = z;
  }

  // L_out: 101,151,201,251 (R=4) ; 301,351 (R=8) ; 401 in registers (last)
  conv_step<4>(gp + 1 * N_ATOM, b0, b1, lane);
  conv_step<4>(gp + 2 * N_ATOM, b1, b0, lane);
  conv_step<4>(gp + 3 * N_ATOM, b0, b1, lane);
  conv_step<4>(gp + 4 * N_ATOM, b1, b0, lane);
  conv_step<8>(gp + 5 * N_ATOM, b0, b1, lane);
  conv_step<8>(gp + 6 * N_ATOM, b1, b0, lane);

  float acc[8];
  conv_body<8>(gp + 7 * N_ATOM, b0, acc, lane);

  // Projection epilogue; q beyond 400 is exact 0 so unguarded sums are safe.
  float s0 = 0.f, s1 = 0.f;
  float* o = out + (size_t)task * N_ATOM;
#pragma unroll
  for (int r = 0; r < 8; ++r) {
    const int oidx = 8 * lane + r;           // 0..511
    if (oidx >= 176 && oidx < 225) o[oidx - 175] = acc[r];
    s0 += (oidx < 176) ? acc[r] : 0.f;
    s1 += (oidx >= 225) ? acc[r] : 0.f;
  }
#pragma unroll
  for (int d = 1; d < 64; d <<= 1) {
    s0 += __shfl_xor(s0, d, 64);
    s1 += __shfl_xor(s1, d, 64);
  }
  if (lane == 0) { o[0] = s0; o[50] = s1; }
}

extern "C" void kernel_launch(void* const* d_in, const int* in_sizes, int n_in,
                              void* d_out, int out_size, void* d_ws, size_t ws_size,
                              hipStream_t stream) {
  const float* agent_qs = (const float*)d_in[0];  // [128,256,8,51] f32
  // d_in[1] (states) is unused by the reference computation
  float* out = (float*)d_out;                     // [128,256,51] f32
  dvdn_mixer_kernel<<<N_TASKS / WPB, 256, 0, stream>>>(agent_qs, out);
}